// Round 6
// baseline (618.117 us; speedup 1.0000x reference)
//
#include <hip/hip_runtime.h>

#define F_FEATS 50000
#define BATCH 16
#define EMBED_DIM 128
#define OUT_DIM 1024
#define TOPK 300
#define SEG 1000
#define NSEG 50            // 50 * 1000 = 50000
#define XSTRIDE 1004       // pad: 1004 % 32 = 12 -> 2-way LDS conflict max
#define JT 32              // j-rows per linear block
#define NLIN (NSEG * (OUT_DIM / JT))   // 50 * 32 = 1600 linear blocks

// ---------------------------------------------------------------------------
// Kernel 1: exact top-300 per row. 4-pass radix select on float bits
// (monotonic for non-negative floats; inputs are uniform [0,1)).
// Wave-level ballot-aggregated histogram atomics + parallel suffix scan.
// One block per batch row, 1024 threads.
// ---------------------------------------------------------------------------
__global__ __launch_bounds__(1024) void topk_kernel(const float* __restrict__ sae,
                                                    int* __restrict__ idxL,
                                                    float* __restrict__ valL) {
  const int b = blockIdx.x;
  const int tid = threadIdx.x;
  const int lane = tid & 63;
  const float* row = sae + (size_t)b * F_FEATS;

  __shared__ unsigned int shist[256];
  __shared__ unsigned int s_prefix, s_rem;
  __shared__ unsigned int s_cnt_gt, s_cnt_eq;
  __shared__ unsigned int eq_idx[256];

  if (tid == 0) { s_prefix = 0u; s_rem = TOPK; }

  const int F_PAD = 50176;   // 49 * 1024: uniform trip count so ballots are wave-uniform

  for (int pass = 0; pass < 4; ++pass) {
    const int shift = 24 - 8 * pass;
    __syncthreads();                       // prev pass's select visible
    const unsigned int prefix = s_prefix;
    const unsigned int rem = s_rem;
    if (tid < 256) shist[tid] = 0u;
    __syncthreads();

    for (int i0 = 0; i0 < F_PAD; i0 += 1024) {
      const int i = i0 + tid;
      const bool inb = i < F_FEATS;
      const unsigned int k = inb ? __float_as_uint(row[i]) : 0u;
      const bool act = inb && ((pass == 0) || ((k >> (shift + 8)) == prefix));
      const unsigned int dgt = (k >> shift) & 255u;
      // match_any emulation: mask of active lanes sharing my digit
      unsigned long long m = __ballot(act);
      #pragma unroll
      for (int bit = 0; bit < 8; ++bit) {
        unsigned long long bb = __ballot((dgt >> bit) & 1u);
        m &= ((dgt >> bit) & 1u) ? bb : ~bb;
      }
      if (act) {
        int leader = __ffsll((unsigned long long)m) - 1;
        if (lane == leader) atomicAdd(&shist[dgt], (unsigned int)__popcll(m));
      }
    }
    __syncthreads();

    // parallel suffix scan: shist[v] := sum_{u>=v} shist[u]
    for (int d = 1; d < 256; d <<= 1) {
      unsigned int t = 0u;
      if (tid < 256 && tid + d < 256) t = shist[tid + d];
      __syncthreads();
      if (tid < 256) shist[tid] += t;
      __syncthreads();
    }
    // select: unique v with S(v) >= rem > S(v+1)
    if (tid < 256) {
      unsigned int Sv = shist[tid];
      unsigned int Sn = (tid < 255) ? shist[tid + 1] : 0u;
      if (Sv >= rem && Sn < rem) {
        s_prefix = (prefix << 8) | (unsigned int)tid;
        s_rem = rem - Sn;
      }
    }
  }
  __syncthreads();

  const unsigned int T = s_prefix;   // exact 32-bit key of the 300th largest
  if (tid == 0) { s_cnt_gt = 0u; s_cnt_eq = 0u; }
  __syncthreads();

  for (int i = tid; i < F_FEATS; i += 1024) {
    float x = row[i];
    unsigned int k = __float_as_uint(x);
    if (k > T) {
      unsigned int p = atomicAdd(&s_cnt_gt, 1u);
      idxL[b * TOPK + p] = i;
      valL[b * TOPK + p] = x;
    } else if (k == T) {
      unsigned int p = atomicAdd(&s_cnt_eq, 1u);
      if (p < 256u) eq_idx[p] = (unsigned int)i;
    }
  }
  __syncthreads();

  if (tid == 0) {
    int cgt = (int)s_cnt_gt;
    int need = TOPK - cgt;                  // how many ==T elements to keep (lowest idx first)
    int m = (int)s_cnt_eq; if (m > 256) m = 256;
    for (int n = 0; n < need; ++n) {
      int best = -1; unsigned int bi = 0x7fffffffu;
      for (int q = 0; q < m; ++q) {
        if (eq_idx[q] < bi) { bi = eq_idx[q]; best = q; }
      }
      int outi = 0; float outv = 0.f;
      if (best >= 0) { eq_idx[best] = 0x7fffffffu; outi = (int)bi; outv = __uint_as_float(T); }
      idxL[b * TOPK + cgt + n] = outi;
      valL[b * TOPK + cgt + n] = outv;
    }
  }
}

// ---------------------------------------------------------------------------
// Kernel 2 (fused): blocks 0..1599 = dense-stream linear partials
// (each block: one 1000-feature segment x 32 j-rows x all 16 batches;
//  sparse x built straight into padded LDS from (idx,val) lists;
//  lin_w read exactly once, fully coalesced float4; partials accumulated
//  into a zeroed 16K-float buffer via atomicAdd -> tiny ws footprint),
// blocks 1600..1615 = FM interaction + MLP (independent of linear).
// 512 threads.
// ---------------------------------------------------------------------------
__global__ __launch_bounds__(512) void fused_kernel(const int* __restrict__ idxL,
                                                    const float* __restrict__ valL,
                                                    const float* __restrict__ lin_w,
                                                    const float* __restrict__ emb,
                                                    const float* __restrict__ w1,
                                                    const float* __restrict__ b1,
                                                    const float* __restrict__ w2,
                                                    const float* __restrict__ b2,
                                                    float* __restrict__ accbuf,
                                                    float* __restrict__ inter_out) {
  __shared__ float smem[BATCH * XSTRIDE];   // 64.25 KB -> 2 blocks/CU
  const int blk = blockIdx.x;
  const int tid = threadIdx.x;

  if (blk < NLIN) {
    const int jg = blk & 31;          // 32 j-groups
    const int seg = blk >> 5;         // 50 segments
    const int f0 = seg * SEG;

    // zero x tile (incl. padding)
    float4* sm4 = (float4*)smem;
    for (int v = tid; v < (BATCH * XSTRIDE) / 4; v += 512)
      sm4[v] = make_float4(0.f, 0.f, 0.f, 0.f);
    __syncthreads();

    // scatter this segment's active features into LDS
    for (int e = tid; e < BATCH * TOPK; e += 512) {
      int i = idxL[e];
      int rel = i - f0;
      if ((unsigned)rel < (unsigned)SEG) {
        int bb = e / TOPK;
        smem[bb * XSTRIDE + rel] = valL[e];
      }
    }
    __syncthreads();

    const int j = tid >> 4;           // 0..31
    const int bb = tid & 15;          // 0..15
    const int rowj = jg * JT + j;
    const float* wr = lin_w + (size_t)rowj * F_FEATS + f0;
    const float* xr = smem + bb * XSTRIDE;

    float acc = 0.f;
    #pragma unroll 4
    for (int f = 0; f < SEG; f += 4) {
      float4 w4 = *(const float4*)(wr + f);
      float4 x4 = *(const float4*)(xr + f);
      acc = fmaf(w4.x, x4.x, acc);
      acc = fmaf(w4.y, x4.y, acc);
      acc = fmaf(w4.z, x4.z, acc);
      acc = fmaf(w4.w, x4.w, acc);
    }
    atomicAdd(&accbuf[bb * OUT_DIM + rowj], acc);
  } else {
    // ------------------- FM + MLP path -------------------
    const int b = blk - NLIN;
    const int kh = tid >> 7;    // 0..3
    const int d  = tid & 127;
    float* s_se  = smem;              // 4*128
    float* s_ssq = smem + 512;        // 4*128
    float* s_iv  = smem + 1024;       // 128
    float* s_h   = smem + 1152;       // 128

    float se = 0.f, ssq = 0.f;
    const int kbeg = kh * 75, kend = kbeg + 75;
    for (int k0 = kbeg; k0 < kend; k0 += 8) {
      int ii[8]; float vv[8];
      #pragma unroll
      for (int u = 0; u < 8; ++u) {
        int k = k0 + u; bool ok = k < kend;
        ii[u] = ok ? idxL[b * TOPK + k] : 0;
        vv[u] = ok ? valL[b * TOPK + k] : 0.f;
      }
      #pragma unroll
      for (int u = 0; u < 8; ++u) {
        float e = emb[(size_t)ii[u] * EMBED_DIM + d];
        float p = vv[u] * e;
        se += p;
        ssq = fmaf(p, p, ssq);
      }
    }
    s_se[kh * 128 + d] = se; s_ssq[kh * 128 + d] = ssq;
    __syncthreads();

    if (tid < 128) {
      float tse = s_se[d] + s_se[128 + d] + s_se[256 + d] + s_se[384 + d];
      float tsq = s_ssq[d] + s_ssq[128 + d] + s_ssq[256 + d] + s_ssq[384 + d];
      s_iv[d] = 0.5f * (tse * tse - tsq);
    }
    __syncthreads();

    if (tid < 128) {
      float a = b1[d];
      #pragma unroll 4
      for (int e = 0; e < 128; ++e) a = fmaf(s_iv[e], w1[d * 128 + e], a);
      s_h[d] = fmaxf(a, 0.f);
    }
    __syncthreads();

    #pragma unroll
    for (int r = 0; r < 2; ++r) {
      int jj = tid + (r << 9);
      float a = b2[jj];
      #pragma unroll 4
      for (int e = 0; e < 128; ++e) a = fmaf(s_h[e], w2[(size_t)jj * 128 + e], a);
      inter_out[b * OUT_DIM + jj] = a;
    }
  }
}

// ---------------------------------------------------------------------------
// Kernel 3: epilogue — add bias, final output sum. 16384 threads.
// ---------------------------------------------------------------------------
__global__ __launch_bounds__(256) void epilogue_kernel(const float* __restrict__ accbuf,
                                                       const float* __restrict__ lin_b,
                                                       const float* __restrict__ inter_out,
                                                       float* __restrict__ out_sum,
                                                       float* __restrict__ out_lin) {
  const int g = blockIdx.x * 256 + threadIdx.x;   // 0..16383 = b*1024 + j
  const int j = g & 1023;
  float lo = accbuf[g] + lin_b[j];
  out_lin[g] = lo;
  out_sum[g] = lo + inter_out[g];
}

extern "C" void kernel_launch(void* const* d_in, const int* in_sizes, int n_in,
                              void* d_out, int out_size, void* d_ws, size_t ws_size,
                              hipStream_t stream) {
  const float* sae   = (const float*)d_in[0];
  const float* emb   = (const float*)d_in[1];
  const float* lin_w = (const float*)d_in[2];
  const float* lin_b = (const float*)d_in[3];
  const float* w1    = (const float*)d_in[4];
  const float* b1    = (const float*)d_in[5];
  const float* w2    = (const float*)d_in[6];
  const float* b2    = (const float*)d_in[7];

  float* out = (float*)d_out;
  float* out_sum = out;                          // output
  float* out_lin = out + BATCH * OUT_DIM;        // linear_out
  float* out_int = out + 2 * BATCH * OUT_DIM;    // interaction_out

  float* valL   = (float*)d_ws;                                         // 4800 f32
  int*   idxL   = (int*)((char*)d_ws + BATCH * TOPK * sizeof(float));   // 4800 i32
  float* accbuf = (float*)((char*)d_ws + 2 * BATCH * TOPK * sizeof(float)); // 16384 f32
  // total ws use: 38.4 KB + 64 KB = ~102 KB

  hipMemsetAsync(accbuf, 0, BATCH * OUT_DIM * sizeof(float), stream);
  hipLaunchKernelGGL(topk_kernel, dim3(BATCH), dim3(1024), 0, stream,
                     sae, idxL, valL);
  hipLaunchKernelGGL(fused_kernel, dim3(NLIN + BATCH), dim3(512), 0, stream,
                     idxL, valL, lin_w, emb, w1, b1, w2, b2, accbuf, out_int);
  hipLaunchKernelGGL(epilogue_kernel, dim3(BATCH * OUT_DIM / 256), dim3(256), 0, stream,
                     accbuf, lin_b, out_int, out_sum, out_lin);
}

// Round 7
// 466.626 us; speedup vs baseline: 1.3247x; 1.3247x over previous
//
#include <hip/hip_runtime.h>

#define F_FEATS 50000
#define BATCH 16
#define EMBED_DIM 128
#define OUT_DIM 1024
#define TOPK 300

// ---------------------------------------------------------------------------
// Kernel 1: exact top-300 per row. 4-pass radix select on float bits
// (monotonic for non-negative floats; inputs are uniform [0,1)).
// Wave-level ballot-aggregated histogram atomics + parallel suffix scan.
// One block per batch row, 1024 threads.
// ---------------------------------------------------------------------------
__global__ __launch_bounds__(1024) void topk_kernel(const float* __restrict__ sae,
                                                    int* __restrict__ idxL,
                                                    float* __restrict__ valL) {
  const int b = blockIdx.x;
  const int tid = threadIdx.x;
  const int lane = tid & 63;
  const float* row = sae + (size_t)b * F_FEATS;

  __shared__ unsigned int shist[256];
  __shared__ unsigned int s_prefix, s_rem;
  __shared__ unsigned int s_cnt_gt, s_cnt_eq;
  __shared__ unsigned int eq_idx[256];

  if (tid == 0) { s_prefix = 0u; s_rem = TOPK; }

  const int F_PAD = 50176;   // 49 * 1024: uniform trip count so ballots are wave-uniform

  for (int pass = 0; pass < 4; ++pass) {
    const int shift = 24 - 8 * pass;
    __syncthreads();                       // prev pass's select visible
    const unsigned int prefix = s_prefix;
    const unsigned int rem = s_rem;
    if (tid < 256) shist[tid] = 0u;
    __syncthreads();

    for (int i0 = 0; i0 < F_PAD; i0 += 1024) {
      const int i = i0 + tid;
      const bool inb = i < F_FEATS;
      const unsigned int k = inb ? __float_as_uint(row[i]) : 0u;
      const bool act = inb && ((pass == 0) || ((k >> (shift + 8)) == prefix));
      const unsigned int dgt = (k >> shift) & 255u;
      // match_any emulation: mask of active lanes sharing my digit
      unsigned long long m = __ballot(act);
      #pragma unroll
      for (int bit = 0; bit < 8; ++bit) {
        unsigned long long bb = __ballot((dgt >> bit) & 1u);
        m &= ((dgt >> bit) & 1u) ? bb : ~bb;
      }
      if (act) {
        int leader = __ffsll((unsigned long long)m) - 1;
        if (lane == leader) atomicAdd(&shist[dgt], (unsigned int)__popcll(m));
      }
    }
    __syncthreads();

    // parallel suffix scan: shist[v] := sum_{u>=v} shist[u]
    for (int d = 1; d < 256; d <<= 1) {
      unsigned int t = 0u;
      if (tid < 256 && tid + d < 256) t = shist[tid + d];
      __syncthreads();
      if (tid < 256) shist[tid] += t;
      __syncthreads();
    }
    // select: unique v with S(v) >= rem > S(v+1)
    if (tid < 256) {
      unsigned int Sv = shist[tid];
      unsigned int Sn = (tid < 255) ? shist[tid + 1] : 0u;
      if (Sv >= rem && Sn < rem) {
        s_prefix = (prefix << 8) | (unsigned int)tid;
        s_rem = rem - Sn;
      }
    }
  }
  __syncthreads();

  const unsigned int T = s_prefix;   // exact 32-bit key of the 300th largest
  if (tid == 0) { s_cnt_gt = 0u; s_cnt_eq = 0u; }
  __syncthreads();

  for (int i = tid; i < F_FEATS; i += 1024) {
    float x = row[i];
    unsigned int k = __float_as_uint(x);
    if (k > T) {
      unsigned int p = atomicAdd(&s_cnt_gt, 1u);
      idxL[b * TOPK + p] = i;
      valL[b * TOPK + p] = x;
    } else if (k == T) {
      unsigned int p = atomicAdd(&s_cnt_eq, 1u);
      if (p < 256u) eq_idx[p] = (unsigned int)i;
    }
  }
  __syncthreads();

  if (tid == 0) {
    int cgt = (int)s_cnt_gt;
    int need = TOPK - cgt;                  // how many ==T elements to keep (lowest idx first)
    int m = (int)s_cnt_eq; if (m > 256) m = 256;
    for (int n = 0; n < need; ++n) {
      int best = -1; unsigned int bi = 0x7fffffffu;
      for (int q = 0; q < m; ++q) {
        if (eq_idx[q] < bi) { bi = eq_idx[q]; best = q; }
      }
      int outi = 0; float outv = 0.f;
      if (best >= 0) { eq_idx[best] = 0x7fffffffu; outi = (int)bi; outv = __uint_as_float(T); }
      idxL[b * TOPK + cgt + n] = outi;
      valL[b * TOPK + cgt + n] = outv;
    }
  }
}

// ---------------------------------------------------------------------------
// Kernel 2: FM interaction + 2-layer MLP, fused. One block per batch row,
// 512 threads = 4 k-phases x 128 dims.
// ---------------------------------------------------------------------------
__global__ __launch_bounds__(512) void fm_mlp_kernel(const int* __restrict__ idxL,
                                                     const float* __restrict__ valL,
                                                     const float* __restrict__ emb,
                                                     const float* __restrict__ w1,
                                                     const float* __restrict__ b1,
                                                     const float* __restrict__ w2,
                                                     const float* __restrict__ b2,
                                                     float* __restrict__ inter_out) {
  const int b = blockIdx.x;
  const int tid = threadIdx.x;
  const int kh = tid >> 7;    // 0..3
  const int d  = tid & 127;

  __shared__ float s_se[4][128], s_ssq[4][128];
  __shared__ float s_iv[128], s_h[128];

  float se = 0.f, ssq = 0.f;
  const int kbeg = kh * 75, kend = kbeg + 75;   // 300/4 = 75
  for (int k0 = kbeg; k0 < kend; k0 += 8) {
    int ii[8]; float vv[8];
    #pragma unroll
    for (int u = 0; u < 8; ++u) {
      int k = k0 + u; bool ok = k < kend;
      ii[u] = ok ? idxL[b * TOPK + k] : 0;
      vv[u] = ok ? valL[b * TOPK + k] : 0.f;
    }
    #pragma unroll
    for (int u = 0; u < 8; ++u) {
      float e = emb[(size_t)ii[u] * EMBED_DIM + d];
      float p = vv[u] * e;
      se += p;
      ssq = fmaf(p, p, ssq);
    }
  }
  s_se[kh][d] = se; s_ssq[kh][d] = ssq;
  __syncthreads();

  if (tid < 128) {
    float tse = s_se[0][d] + s_se[1][d] + s_se[2][d] + s_se[3][d];
    float tsq = s_ssq[0][d] + s_ssq[1][d] + s_ssq[2][d] + s_ssq[3][d];
    s_iv[d] = 0.5f * (tse * tse - tsq);
  }
  __syncthreads();

  if (tid < 128) {
    float a = b1[d];
    #pragma unroll 4
    for (int e = 0; e < 128; ++e) a = fmaf(s_iv[e], w1[d * 128 + e], a);
    s_h[d] = fmaxf(a, 0.f);
  }
  __syncthreads();

  #pragma unroll
  for (int r = 0; r < 2; ++r) {
    int j = tid + (r << 9);
    float a = b2[j];
    #pragma unroll 4
    for (int e = 0; e < 128; ++e) a = fmaf(s_h[e], w2[(size_t)j * 128 + e], a);
    inter_out[b * OUT_DIM + j] = a;
  }
}

// ---------------------------------------------------------------------------
// Kernel 3: sparse linear layer + final sum. One block per output row j
// (1024 blocks), 512 threads = 16 batches x 32 k-slices, 10 gathers/thread.
// 8 waves/block, ~4 blocks/CU -> full occupancy; each block's ~4800 gathers
// hit row j's ~157 KB line set exactly once (no cross-block reuse needed).
// ---------------------------------------------------------------------------
__global__ __launch_bounds__(512) void linear_kernel(const int* __restrict__ idxL,
                                                     const float* __restrict__ valL,
                                                     const float* __restrict__ lin_w,
                                                     const float* __restrict__ lin_b,
                                                     const float* __restrict__ inter_out,
                                                     float* __restrict__ out_sum,
                                                     float* __restrict__ out_lin) {
  const int j = blockIdx.x;
  const int t = threadIdx.x;
  const int bb = t >> 5;      // 0..15
  const int s  = t & 31;      // 0..31
  const float* wrow = lin_w + (size_t)j * F_FEATS;

  // 300 = 9*32 + 12 -> s<12 threads own 10 elems, others 9 (padded with 0s)
  int ii[10]; float vv[10];
  #pragma unroll
  for (int u = 0; u < 10; ++u) {
    int k = s + (u << 5);
    bool ok = k < TOPK;
    ii[u] = ok ? idxL[bb * TOPK + k] : 0;
    vv[u] = ok ? valL[bb * TOPK + k] : 0.f;
  }
  float acc = 0.f;
  #pragma unroll
  for (int u = 0; u < 10; ++u) acc = fmaf(vv[u], wrow[ii[u]], acc);

  // reduce over the 32 k-slices (lanes s=0..31 within each half-wave)
  acc += __shfl_down(acc, 16, 32);
  acc += __shfl_down(acc, 8, 32);
  acc += __shfl_down(acc, 4, 32);
  acc += __shfl_down(acc, 2, 32);
  acc += __shfl_down(acc, 1, 32);

  if (s == 0) {
    float lo = acc + lin_b[j];
    out_lin[bb * OUT_DIM + j] = lo;
    out_sum[bb * OUT_DIM + j] = lo + inter_out[bb * OUT_DIM + j];
  }
}

extern "C" void kernel_launch(void* const* d_in, const int* in_sizes, int n_in,
                              void* d_out, int out_size, void* d_ws, size_t ws_size,
                              hipStream_t stream) {
  const float* sae   = (const float*)d_in[0];
  const float* emb   = (const float*)d_in[1];
  const float* lin_w = (const float*)d_in[2];
  const float* lin_b = (const float*)d_in[3];
  const float* w1    = (const float*)d_in[4];
  const float* b1    = (const float*)d_in[5];
  const float* w2    = (const float*)d_in[6];
  const float* b2    = (const float*)d_in[7];

  float* out = (float*)d_out;
  float* out_sum = out;                          // output
  float* out_lin = out + BATCH * OUT_DIM;        // linear_out
  float* out_int = out + 2 * BATCH * OUT_DIM;    // interaction_out

  float* valL = (float*)d_ws;                                        // 4800 f32
  int*   idxL = (int*)((char*)d_ws + BATCH * TOPK * sizeof(float));  // 4800 i32

  hipLaunchKernelGGL(topk_kernel, dim3(BATCH), dim3(1024), 0, stream,
                     sae, idxL, valL);
  hipLaunchKernelGGL(fm_mlp_kernel, dim3(BATCH), dim3(512), 0, stream,
                     idxL, valL, emb, w1, b1, w2, b2, out_int);
  hipLaunchKernelGGL(linear_kernel, dim3(OUT_DIM), dim3(512), 0, stream,
                     idxL, valL, lin_w, lin_b, out_int, out_sum, out_lin);
}

// Round 8
// 450.887 us; speedup vs baseline: 1.3709x; 1.0349x over previous
//
#include <hip/hip_runtime.h>

#define F_FEATS 50000
#define BATCH 16
#define EMBED_DIM 128
#define OUT_DIM 1024
#define TOPK 300
#define CAP 4096
#define T0BITS 0x3F7C0000u   // bits of 0.984375f; top-300/50000 quantile ~0.994 >> this

// ---------------------------------------------------------------------------
// Kernel 1a: candidate filter. 256 blocks (16 rows x 16 chunks), 256 threads.
// Appends (idx,val) of elements >= 0.984375 to per-row candidate lists via
// wave-aggregated atomics. Expected ~781 candidates/row for uniform input.
// cand_cnt counts ALL qualifying elements (even if > CAP) so the select
// kernel can detect overflow and fall back.
// ---------------------------------------------------------------------------
__global__ __launch_bounds__(256) void filter_kernel(const float* __restrict__ sae,
                                                     float* __restrict__ cand_val,
                                                     int* __restrict__ cand_idx,
                                                     unsigned int* __restrict__ cand_cnt) {
  const int b = blockIdx.x >> 4;
  const int c = blockIdx.x & 15;
  const int tid = threadIdx.x;
  const int lane = tid & 63;
  const float* row = sae + (size_t)b * F_FEATS;
  const int beg = c * 3125, end = beg + 3125;   // 16*3125 = 50000

  for (int i0 = beg; i0 < end; i0 += 256) {
    const int i = i0 + tid;
    bool q = false; float x = 0.f;
    if (i < end) { x = row[i]; q = (__float_as_uint(x) >= T0BITS); }
    unsigned long long m = __ballot(q);
    if (m == 0ull) continue;                      // wave-uniform
    const int leader = __ffsll(m) - 1;
    unsigned int base = 0u;
    if (lane == leader) base = atomicAdd(&cand_cnt[b], (unsigned int)__popcll(m));
    base = __shfl(base, leader);
    if (q) {
      unsigned int off = base + (unsigned int)__popcll(m & ((1ull << lane) - 1ull));
      if (off < CAP) { cand_val[b * CAP + off] = x; cand_idx[b * CAP + off] = i; }
    }
  }
}

// ---------------------------------------------------------------------------
// Kernel 1b: exact top-300 select over the candidate list (LDS radix select,
// 4x8-bit passes). Tie-break: keep lowest indices (matches lax.top_k set).
// Fallback: if cnt < TOPK or cnt > CAP, radix-select over the full row from
// global memory (correct for any input; never triggers for uniform input).
// 16 blocks (one per row), 256 threads.
// ---------------------------------------------------------------------------
__global__ __launch_bounds__(256) void select_kernel(const float* __restrict__ sae,
                                                     const float* __restrict__ cand_val,
                                                     const int* __restrict__ cand_idx,
                                                     const unsigned int* __restrict__ cand_cnt,
                                                     int* __restrict__ idxL,
                                                     float* __restrict__ valL) {
  const int b = blockIdx.x;
  const int tid = threadIdx.x;
  const int wave = tid >> 6;
  const float* row = sae + (size_t)b * F_FEATS;

  __shared__ float cval[CAP];
  __shared__ int   cidx[CAP];
  __shared__ unsigned int whist[4][256];
  __shared__ unsigned int shist[256];
  __shared__ unsigned int s_prefix, s_rem, s_cnt_gt, s_cnt_eq;
  __shared__ unsigned int eq_pos[512];

  const unsigned int cnt = cand_cnt[b];
  const bool fast = (cnt >= TOPK && cnt <= CAP);
  const int n = fast ? (int)cnt : F_FEATS;

  if (fast) {
    for (int i = tid; i < n; i += 256) {
      cval[i] = cand_val[b * CAP + i];
      cidx[i] = cand_idx[b * CAP + i];
    }
  }
  if (tid == 0) { s_prefix = 0u; s_rem = TOPK; }

  for (int pass = 0; pass < 4; ++pass) {
    const int shift = 24 - 8 * pass;
    __syncthreads();                         // select (and cval load) visible
    const unsigned int prefix = s_prefix;
    const unsigned int rem = s_rem;
    #pragma unroll
    for (int v = 0; v < 4; ++v) whist[v][tid] = 0u;
    __syncthreads();

    for (int i = tid; i < n; i += 256) {
      unsigned int k = __float_as_uint(fast ? cval[i] : row[i]);
      bool act = (pass == 0) || ((k >> (shift + 8)) == prefix);
      if (act) atomicAdd(&whist[wave][(k >> shift) & 255u], 1u);
    }
    __syncthreads();
    shist[tid] = whist[0][tid] + whist[1][tid] + whist[2][tid] + whist[3][tid];
    __syncthreads();
    // suffix scan: shist[v] := sum_{u>=v}
    for (int d = 1; d < 256; d <<= 1) {
      unsigned int t = (tid + d < 256) ? shist[tid + d] : 0u;
      __syncthreads();
      shist[tid] += t;
      __syncthreads();
    }
    {
      unsigned int Sv = shist[tid];
      unsigned int Sn = (tid < 255) ? shist[tid + 1] : 0u;
      if (Sv >= rem && Sn < rem) {        // unique boundary digit
        s_prefix = (prefix << 8) | (unsigned int)tid;
        s_rem = rem - Sn;
      }
    }
  }
  __syncthreads();
  const unsigned int T = s_prefix;         // exact bits of the 300th largest
  if (tid == 0) { s_cnt_gt = 0u; s_cnt_eq = 0u; }
  __syncthreads();

  for (int i = tid; i < n; i += 256) {
    float x = fast ? cval[i] : row[i];
    int idx = fast ? cidx[i] : i;
    unsigned int k = __float_as_uint(x);
    if (k > T) {
      unsigned int p = atomicAdd(&s_cnt_gt, 1u);
      idxL[b * TOPK + p] = idx;
      valL[b * TOPK + p] = x;
    } else if (k == T) {
      unsigned int p = atomicAdd(&s_cnt_eq, 1u);
      if (p < 512u) eq_pos[p] = (unsigned int)idx;
    }
  }
  __syncthreads();

  if (tid == 0) {                           // fill ties, lowest index first
    int cgt = (int)s_cnt_gt;
    int need = TOPK - cgt;
    int m = (int)s_cnt_eq; if (m > 512) m = 512;
    for (int nf = 0; nf < need; ++nf) {
      unsigned int bi = 0xffffffffu; int best = -1;
      for (int q = 0; q < m; ++q)
        if (eq_pos[q] < bi) { bi = eq_pos[q]; best = q; }
      int outi = 0; float outv = 0.f;
      if (best >= 0) { eq_pos[best] = 0xffffffffu; outi = (int)bi; outv = __uint_as_float(T); }
      idxL[b * TOPK + cgt + nf] = outi;
      valL[b * TOPK + cgt + nf] = outv;
    }
  }
}

// ---------------------------------------------------------------------------
// Kernel 2: FM interaction + 2-layer MLP, fused. One block per batch row,
// 512 threads = 4 k-phases x 128 dims.
// ---------------------------------------------------------------------------
__global__ __launch_bounds__(512) void fm_mlp_kernel(const int* __restrict__ idxL,
                                                     const float* __restrict__ valL,
                                                     const float* __restrict__ emb,
                                                     const float* __restrict__ w1,
                                                     const float* __restrict__ b1,
                                                     const float* __restrict__ w2,
                                                     const float* __restrict__ b2,
                                                     float* __restrict__ inter_out) {
  const int b = blockIdx.x;
  const int tid = threadIdx.x;
  const int kh = tid >> 7;    // 0..3
  const int d  = tid & 127;

  __shared__ float s_se[4][128], s_ssq[4][128];
  __shared__ float s_iv[128], s_h[128];

  float se = 0.f, ssq = 0.f;
  const int kbeg = kh * 75, kend = kbeg + 75;   // 300/4 = 75
  for (int k0 = kbeg; k0 < kend; k0 += 8) {
    int ii[8]; float vv[8];
    #pragma unroll
    for (int u = 0; u < 8; ++u) {
      int k = k0 + u; bool ok = k < kend;
      ii[u] = ok ? idxL[b * TOPK + k] : 0;
      vv[u] = ok ? valL[b * TOPK + k] : 0.f;
    }
    #pragma unroll
    for (int u = 0; u < 8; ++u) {
      float e = emb[(size_t)ii[u] * EMBED_DIM + d];
      float p = vv[u] * e;
      se += p;
      ssq = fmaf(p, p, ssq);
    }
  }
  s_se[kh][d] = se; s_ssq[kh][d] = ssq;
  __syncthreads();

  if (tid < 128) {
    float tse = s_se[0][d] + s_se[1][d] + s_se[2][d] + s_se[3][d];
    float tsq = s_ssq[0][d] + s_ssq[1][d] + s_ssq[2][d] + s_ssq[3][d];
    s_iv[d] = 0.5f * (tse * tse - tsq);
  }
  __syncthreads();

  if (tid < 128) {
    float a = b1[d];
    #pragma unroll 4
    for (int e = 0; e < 128; ++e) a = fmaf(s_iv[e], w1[d * 128 + e], a);
    s_h[d] = fmaxf(a, 0.f);
  }
  __syncthreads();

  #pragma unroll
  for (int r = 0; r < 2; ++r) {
    int j = tid + (r << 9);
    float a = b2[j];
    #pragma unroll 4
    for (int e = 0; e < 128; ++e) a = fmaf(s_h[e], w2[(size_t)j * 128 + e], a);
    inter_out[b * OUT_DIM + j] = a;
  }
}

// ---------------------------------------------------------------------------
// Kernel 3: sparse linear layer + final sum. One block per output row j
// (1024 blocks), 512 threads = 16 batches x 32 k-slices, 10 gathers/thread.
// ---------------------------------------------------------------------------
__global__ __launch_bounds__(512) void linear_kernel(const int* __restrict__ idxL,
                                                     const float* __restrict__ valL,
                                                     const float* __restrict__ lin_w,
                                                     const float* __restrict__ lin_b,
                                                     const float* __restrict__ inter_out,
                                                     float* __restrict__ out_sum,
                                                     float* __restrict__ out_lin) {
  const int j = blockIdx.x;
  const int t = threadIdx.x;
  const int bb = t >> 5;      // 0..15
  const int s  = t & 31;      // 0..31
  const float* wrow = lin_w + (size_t)j * F_FEATS;

  int ii[10]; float vv[10];
  #pragma unroll
  for (int u = 0; u < 10; ++u) {
    int k = s + (u << 5);
    bool ok = k < TOPK;
    ii[u] = ok ? idxL[bb * TOPK + k] : 0;
    vv[u] = ok ? valL[bb * TOPK + k] : 0.f;
  }
  float acc = 0.f;
  #pragma unroll
  for (int u = 0; u < 10; ++u) acc = fmaf(vv[u], wrow[ii[u]], acc);

  acc += __shfl_down(acc, 16, 32);
  acc += __shfl_down(acc, 8, 32);
  acc += __shfl_down(acc, 4, 32);
  acc += __shfl_down(acc, 2, 32);
  acc += __shfl_down(acc, 1, 32);

  if (s == 0) {
    float lo = acc + lin_b[j];
    out_lin[bb * OUT_DIM + j] = lo;
    out_sum[bb * OUT_DIM + j] = lo + inter_out[bb * OUT_DIM + j];
  }
}

extern "C" void kernel_launch(void* const* d_in, const int* in_sizes, int n_in,
                              void* d_out, int out_size, void* d_ws, size_t ws_size,
                              hipStream_t stream) {
  const float* sae   = (const float*)d_in[0];
  const float* emb   = (const float*)d_in[1];
  const float* lin_w = (const float*)d_in[2];
  const float* lin_b = (const float*)d_in[3];
  const float* w1    = (const float*)d_in[4];
  const float* b1    = (const float*)d_in[5];
  const float* w2    = (const float*)d_in[6];
  const float* b2    = (const float*)d_in[7];

  float* out = (float*)d_out;
  float* out_sum = out;                          // output
  float* out_lin = out + BATCH * OUT_DIM;        // linear_out
  float* out_int = out + 2 * BATCH * OUT_DIM;    // interaction_out

  char* ws = (char*)d_ws;
  float*        valL     = (float*)(ws);                   // 4800 f32  (19200 B)
  int*          idxL     = (int*)(ws + 19200);             // 4800 i32  (19200 B)
  float*        cand_val = (float*)(ws + 38400);           // 16*4096 f32 (256 KB)
  int*          cand_idx = (int*)(ws + 38400 + 262144);    // 16*4096 i32 (256 KB)
  unsigned int* cand_cnt = (unsigned int*)(ws + 38400 + 2 * 262144);  // 16 u32
  // total ws use ~563 KB

  hipMemsetAsync(cand_cnt, 0, BATCH * sizeof(unsigned int), stream);
  hipLaunchKernelGGL(filter_kernel, dim3(256), dim3(256), 0, stream,
                     sae, cand_val, cand_idx, cand_cnt);
  hipLaunchKernelGGL(select_kernel, dim3(BATCH), dim3(256), 0, stream,
                     sae, cand_val, cand_idx, cand_cnt, idxL, valL);
  hipLaunchKernelGGL(fm_mlp_kernel, dim3(BATCH), dim3(512), 0, stream,
                     idxL, valL, emb, w1, b1, w2, b2, out_int);
  hipLaunchKernelGGL(linear_kernel, dim3(OUT_DIM), dim3(512), 0, stream,
                     idxL, valL, lin_w, lin_b, out_int, out_sum, out_lin);
}